// Round 3
// baseline (216.897 us; speedup 1.0000x reference)
//
#pragma clang fp contract(off)
#include <hip/hip_runtime.h>
#include <math.h>

#define G       104
#define NBA     9
#define NC      80
#define NBOX    (G*G*NBA)      // 97344
#define CH      (5+NC)         // 85
#define DET_T_  0.02f
#define NMS_T_  0.3f
#define MAXB    50
#define CAP     2048
#define NSLOT   (CAP/64)       // 32 candidate slots per lane
#define IMG     832
#define CSTRIDE 16             // pad class counters to 64B (separate L2 lines)
#define DB      128            // decode boxes per block

typedef unsigned long long u64;
typedef unsigned int       u32;

__device__ __forceinline__ float sigmoidf_(float x) { return 1.0f / (1.0f + expf(-x)); }

// ---------------- decode + per-class compaction (LDS-staged, coalesced) ----------------
__global__ __launch_bounds__(DB) void decode_kernel(const float* __restrict__ in,
        const float* __restrict__ anchors, int* __restrict__ cnt,
        float4* __restrict__ candBox, float* __restrict__ candScore, int* __restrict__ candIdx)
{
    __shared__ float lds[DB * CH];   // 43,520 B
    const int tid = threadIdx.x;
    const int base = blockIdx.x * (DB * CH);
    int nfl = NBOX * CH - base;
    if (nfl > DB * CH) nfl = DB * CH;

    int nv4 = nfl >> 2;
    const float4* gin4 = (const float4*)(in + base);
    for (int i = tid; i < nv4; i += DB) ((float4*)lds)[i] = gin4[i];
    for (int i = (nv4 << 2) + tid; i < nfl; i += DB) lds[i] = in[base + i];
    __syncthreads();

    int n = blockIdx.x * DB + tid;
    if (n >= NBOX) return;
    const float* p = lds + tid * CH;

    // softmax over p[5..84]: exp(x - max) / sum  (exact reference op order)
    float m = -INFINITY;
    for (int i = 0; i < NC; ++i) m = fmaxf(m, p[5 + i]);
    float sum = 0.0f;
    for (int i = 0; i < NC; ++i) sum += expf(p[5 + i] - m);
    float obj = sigmoidf_(p[4]);

    // first-max argmax over s_i = obj * (e_i / sum)
    float best = -1.0f; int bcls = 0;
    for (int i = 0; i < NC; ++i) {
        float e = expf(p[5 + i] - m);
        float s = obj * (e / sum);
        if (s > best) { best = s; bcls = i; }
    }

    if (best > DET_T_) {
        int a  = n % NBA;
        int t  = n / NBA;
        int gx = t % G;
        int gy = t / G;
        float bx = (sigmoidf_(p[0]) + (float)gx) / (float)G;
        float by = (sigmoidf_(p[1]) + (float)gy) / (float)G;
        float bw = expf(p[2]) * anchors[2*a + 0] / (float)G;
        float bh = expf(p[3]) * anchors[2*a + 1] / (float)G;
        float4 box = make_float4(bx - bw / 2.0f, by - bh / 2.0f,
                                 bx + bw / 2.0f, by + bh / 2.0f);
        int pos = atomicAdd(&cnt[bcls * CSTRIDE], 1);
        if (pos < CAP) {
            int slot = bcls * CAP + pos;
            candBox[slot]   = box;
            candScore[slot] = best;
            candIdx[slot]   = n;
        }
    }
}

// ---------------- per-class greedy NMS: ONE WAVE per class, zero barriers ----------------
// key = (score_bits << 32) | ~id : u64 max == (max score, tie -> min original index)
__global__ __launch_bounds__(64) void nms_kernel(const int* __restrict__ cnt,
    const float4* __restrict__ candBox, const float* __restrict__ candScore,
    const int* __restrict__ candIdx, float4* __restrict__ selBox, int* __restrict__ selValid)
{
    __shared__ float4 sbox[CAP];     // 32 KB
    const int c    = blockIdx.x;
    const int lane = threadIdx.x;
    int count = cnt[c * CSTRIDE]; if (count > CAP) count = CAP;

    u64 key[NSLOT];
#pragma unroll
    for (int j = 0; j < NSLOT; ++j) {
        int i = (j << 6) + lane;
        u64 k = 0;
        float4 b = make_float4(0, 0, 0, 0);
        if (i < count) {
            float s = candScore[c*CAP + i];
            int  id = candIdx[c*CAP + i];
            b       = candBox[c*CAP + i];
            k = ((u64)__float_as_uint(s) << 32) | (u32)(~(u32)id);
        }
        key[j] = k;
        sbox[i] = b;
    }
    if (lane < MAXB) selValid[c*MAXB + lane] = 0;
    __syncthreads();   // single wave: just orders LDS writes before reads

    float4 W = make_float4(0, 0, 0, 0);

    for (int k = 0; k < MAXB; ++k) {
        u64 lbest = 0; int jbest = 0;

        if (k == 0) {
#pragma unroll
            for (int j = 0; j < NSLOT; ++j) {
                if ((j << 6) < count) {          // uniform trim
                    u64 kj = key[j];
                    if (kj > lbest) { lbest = kj; jbest = j; }
                }
            }
        } else {
            // fused suppress-vs-W + next-max (sequential reference semantics;
            // winner removes itself via self-IoU == 1 > NMS_T)
            float a0 = (W.z - W.x) * (W.w - W.y);
#pragma unroll
            for (int j = 0; j < NSLOT; ++j) {
                if ((j << 6) < count) {
                    u64 kj = key[j];
                    if (kj != 0) {
                        float4 A = sbox[(j << 6) + lane];
                        float x1 = fmaxf(W.x, A.x), y1 = fmaxf(W.y, A.y);
                        float x2 = fminf(W.z, A.z), y2 = fminf(W.w, A.w);
                        float inter = fmaxf(x2 - x1, 0.0f) * fmaxf(y2 - y1, 0.0f);
                        float a1 = (A.z - A.x) * (A.w - A.y);
                        float uni = a0 + a1 - inter;
                        float iou = (uni > 0.0f) ? (inter / uni) : 0.0f;
                        if (iou > NMS_T_) { kj = 0; key[j] = 0; }
                        if (kj > lbest) { lbest = kj; jbest = j; }
                    }
                }
            }
        }

        // one u64 butterfly max-reduce (6 steps x 2 shuffles)
        u64 lkey = lbest;
        u64 g = lbest;
#pragma unroll
        for (int off = 32; off >= 1; off >>= 1) {
            u64 o = __shfl_xor(g, off);
            if (o > g) g = o;
        }
        if (g == 0) break;   // no candidates left; rest of picks invalid => never drawn

        unsigned long long mask = __ballot(lkey == g);
        int wl = __ffsll((long long)mask) - 1;     // winner lane (unique: keys unique)
        int wj = __shfl(jbest, wl);                // winner slot (uniform)
        W = sbox[(wj << 6) + wl];                  // broadcast read, conflict-free

        if (lane == 0) {
            selBox[c*MAXB + k]   = W;
            selValid[c*MAXB + k] = 1;
        }
    }
}

// ---------------- draw edges ----------------
__device__ __forceinline__ int to_px(float v) {
    float r = rintf(v * 831.0f);           // jnp.round = half-to-even
    r = fminf(fmaxf(r, 0.0f), 831.0f);     // clip AFTER round
    return (int)r;
}

__global__ void draw_kernel(const float4* __restrict__ selBox, const int* __restrict__ selValid,
                            float* __restrict__ out)
{
    int b = blockIdx.x;
    if (!selValid[b]) return;
    float4 B = selBox[b];
    int r1 = to_px(B.x), c1 = to_px(B.y), r2 = to_px(B.z), c2 = to_px(B.w);
    for (int i = threadIdx.x; i <= c2 - c1; i += blockDim.x) {
        out[r1*IMG + c1 + i] = 1.0f;
        out[r2*IMG + c1 + i] = 1.0f;
    }
    for (int i = threadIdx.x; i <= r2 - r1; i += blockDim.x) {
        out[(r1 + i)*IMG + c1] = 1.0f;
        out[(r1 + i)*IMG + c2] = 1.0f;
    }
}

extern "C" void kernel_launch(void* const* d_in, const int* in_sizes, int n_in,
                              void* d_out, int out_size, void* d_ws, size_t ws_size,
                              hipStream_t stream)
{
    const float* in      = (const float*)d_in[0];
    const float* anchors = (const float*)d_in[1];
    float* out           = (float*)d_out;

    char* ws = (char*)d_ws;
    size_t off = 0;
    int*    cnt       = (int*)(ws + off);    off += (size_t)NC*CSTRIDE*sizeof(int);
    float4* candBox   = (float4*)(ws + off); off += (size_t)NC*CAP*sizeof(float4);
    float*  candScore = (float*)(ws + off);  off += (size_t)NC*CAP*sizeof(float);
    int*    candIdx   = (int*)(ws + off);    off += (size_t)NC*CAP*sizeof(int);
    float4* selBox    = (float4*)(ws + off); off += (size_t)NC*MAXB*sizeof(float4);
    int*    selValid  = (int*)(ws + off);    off += (size_t)NC*MAXB*sizeof(int);

    hipMemsetAsync(cnt, 0, (size_t)NC*CSTRIDE*sizeof(int), stream);
    hipMemsetAsync(out, 0, (size_t)IMG*IMG*sizeof(float), stream);

    decode_kernel<<<(NBOX + DB - 1)/DB, DB, 0, stream>>>(in, anchors, cnt, candBox, candScore, candIdx);
    nms_kernel<<<NC, 64, 0, stream>>>(cnt, candBox, candScore, candIdx, selBox, selValid);
    draw_kernel<<<NC*MAXB, 128, 0, stream>>>(selBox, selValid, out);
}

// Round 4
// 118.775 us; speedup vs baseline: 1.8261x; 1.8261x over previous
//
#pragma clang fp contract(off)
#include <hip/hip_runtime.h>
#include <math.h>

#define G       104
#define NBA     9
#define NC      80
#define NBOX    (G*G*NBA)      // 97344
#define CH      (5+NC)         // 85
#define DET_T_  0.02f
#define NMS_T_  0.3f
#define MAXB    50
#define CAP     2048
#define IMG     832
#define CSTRIDE 16             // pad class counters to 64B
#define DB      128            // decode boxes per block

typedef unsigned long long u64;
typedef unsigned int       u32;

__device__ __forceinline__ float sigmoidf_(float x) { return 1.0f / (1.0f + expf(-x)); }

// ---------------- decode + per-class compaction ----------------
// Candidate-window trick: e_max == expf(0) == 1.0 exactly; any class whose
// score could equal the max after div+mul rounding needs x_i - m >= ~-3.6e-7.
// Use -2e-6 window (5x margin, superset) -> compute the exact reference
// expression obj*(expf(x-m)/sum) only for ~1-2 candidate classes.
__global__ __launch_bounds__(DB) void decode_kernel(const float* __restrict__ in,
        const float* __restrict__ anchors, int* __restrict__ cnt,
        float4* __restrict__ candBox, u64* __restrict__ candKey)
{
    __shared__ float lds[DB * CH];   // 43,520 B
    const int tid = threadIdx.x;
    const int base = blockIdx.x * (DB * CH);
    int nfl = NBOX * CH - base;
    if (nfl > DB * CH) nfl = DB * CH;

    int nv4 = nfl >> 2;
    const float4* gin4 = (const float4*)(in + base);
    for (int i = tid; i < nv4; i += DB) ((float4*)lds)[i] = gin4[i];
    for (int i = (nv4 << 2) + tid; i < nfl; i += DB) lds[i] = in[base + i];
    __syncthreads();

    int n = blockIdx.x * DB + tid;
    if (n >= NBOX) return;
    const float* p = lds + tid * CH;

    float m = -INFINITY;
#pragma unroll
    for (int i = 0; i < NC; ++i) m = fmaxf(m, p[5 + i]);

    // single exp pass: sum (exact reference order) + candidate bitmask
    float sum = 0.0f;
    u64 cm0 = 0, cm1 = 0;
#pragma unroll
    for (int i = 0; i < NC; ++i) {
        float d = p[5 + i] - m;
        sum += expf(d);
        u64 cand = (d >= -2.0e-6f) ? 1ull : 0ull;
        if (i < 64) cm0 |= cand << i;
        else        cm1 |= cand << (i - 64);
    }
    float obj = sigmoidf_(p[4]);

    // exact first-max over candidate classes only (ascending index order)
    float best = -1.0f; int bcls = 0;
    while (cm0) {
        int i = __ffsll((long long)cm0) - 1; cm0 &= cm0 - 1;
        float e = expf(p[5 + i] - m);
        float s = obj * (e / sum);
        if (s > best) { best = s; bcls = i; }
    }
    while (cm1) {
        int i = __ffsll((long long)cm1) - 1 + 64; cm1 &= cm1 - 1;
        float e = expf(p[5 + i] - m);
        float s = obj * (e / sum);
        if (s > best) { best = s; bcls = i; }
    }

    if (best > DET_T_) {
        int a  = n % NBA;
        int t  = n / NBA;
        int gx = t % G;
        int gy = t / G;
        float bx = (sigmoidf_(p[0]) + (float)gx) / (float)G;
        float by = (sigmoidf_(p[1]) + (float)gy) / (float)G;
        float bw = expf(p[2]) * anchors[2*a + 0] / (float)G;
        float bh = expf(p[3]) * anchors[2*a + 1] / (float)G;
        float4 box = make_float4(bx - bw / 2.0f, by - bh / 2.0f,
                                 bx + bw / 2.0f, by + bh / 2.0f);
        int pos = atomicAdd(&cnt[bcls * CSTRIDE], 1);
        if (pos < CAP) {
            int slot = bcls * CAP + pos;
            candBox[slot] = box;
            candKey[slot] = ((u64)__float_as_uint(best) << 32) | (u32)(~(u32)n);
        }
    }
}

// ---------------- per-class greedy NMS: 4 waves, 1 barrier/pick ----------------
// key = (score_bits<<32) | ~id : u64 max == (max score, tie -> min original id)
__global__ __launch_bounds__(256) void nms_kernel(const int* __restrict__ cnt,
    const float4* __restrict__ candBox, const u64* __restrict__ candKey,
    float4* __restrict__ selBox, int* __restrict__ selValid)
{
    __shared__ u64    red_k[2][4];
    __shared__ float4 red_b[2][4];

    const int c = blockIdx.x;
    const int t = threadIdx.x;
    int count = cnt[c * CSTRIDE]; if (count > CAP) count = CAP;

    u64 key[8]; float4 bx[8];
#pragma unroll
    for (int j = 0; j < 8; ++j) {
        int i = t + (j << 8);
        if (i < count) { key[j] = candKey[c*CAP + i]; bx[j] = candBox[c*CAP + i]; }
        else           { key[j] = 0; bx[j] = make_float4(0,0,0,0); }
    }
    if (t < MAXB) selValid[c*MAXB + t] = 0;

    float4 W = make_float4(0,0,0,0);

    for (int k = 0; k < MAXB; ++k) {
        u64 lbest = 0; float4 lbox = make_float4(0,0,0,0);

        if (k == 0) {
#pragma unroll
            for (int j = 0; j < 8; ++j) if ((j << 8) < count) {
                if (key[j] > lbest) { lbest = key[j]; lbox = bx[j]; }
            }
        } else {
            // fused suppress-vs-W + next-max (winner removes itself: self-IoU=1>T)
            float a0 = (W.z - W.x) * (W.w - W.y);
#pragma unroll
            for (int j = 0; j < 8; ++j) if ((j << 8) < count) {
                u64 kj = key[j];
                if (kj != 0) {
                    float4 A = bx[j];
                    float x1 = fmaxf(W.x, A.x), y1 = fmaxf(W.y, A.y);
                    float x2 = fminf(W.z, A.z), y2 = fminf(W.w, A.w);
                    float inter = fmaxf(x2 - x1, 0.0f) * fmaxf(y2 - y1, 0.0f);
                    float a1 = (A.z - A.x) * (A.w - A.y);
                    float uni = a0 + a1 - inter;
                    float iou = (uni > 0.0f) ? (inter / uni) : 0.0f;
                    if (iou > NMS_T_) { kj = 0; key[j] = 0; }
                    if (kj > lbest) { lbest = kj; lbox = bx[j]; }
                }
            }
        }

        // wave reduce: key-only u64 butterfly (12 ds-ops), then extract winner box
        u64 mine = lbest;
        u64 gk = lbest;
#pragma unroll
        for (int off = 32; off >= 1; off >>= 1) {
            u64 ok = __shfl_xor(gk, off);
            if (ok > gk) gk = ok;
        }
        unsigned long long wm = __ballot(mine == gk && gk != 0);
        int wl = __ffsll((long long)wm) - 1;       // unique (keys unique); -1 only if gk==0
        float wx = __shfl(lbox.x, wl);
        float wy = __shfl(lbox.y, wl);
        float wz = __shfl(lbox.z, wl);
        float ww = __shfl(lbox.w, wl);

        int wave = t >> 6, lane = t & 63, par = k & 1;
        if (lane == 0) { red_k[par][wave] = gk; red_b[par][wave] = make_float4(wx, wy, wz, ww); }
        __syncthreads();   // single barrier per pick (parity double-buffer)

        u64 k0 = red_k[par][0], k1 = red_k[par][1], k2 = red_k[par][2], k3 = red_k[par][3];
        float4 b0 = red_b[par][0], b1 = red_b[par][1], b2 = red_b[par][2], b3 = red_b[par][3];
        u64 ka, kb, kg; float4 ba, bb, bg;
        if (k0 > k1) { ka = k0; ba = b0; } else { ka = k1; ba = b1; }
        if (k2 > k3) { kb = k2; bb = b2; } else { kb = k3; bb = b3; }
        if (ka > kb) { kg = ka; bg = ba; } else { kg = kb; bg = bb; }

        if (kg == 0) break;    // uniform: pool empty, rest invalid => never drawn

        W = bg;
        if (t == 0) {
            selBox[c*MAXB + k]   = bg;
            selValid[c*MAXB + k] = 1;
        }
    }
}

// ---------------- draw edges ----------------
__device__ __forceinline__ int to_px(float v) {
    float r = rintf(v * 831.0f);           // jnp.round = half-to-even
    r = fminf(fmaxf(r, 0.0f), 831.0f);     // clip AFTER round
    return (int)r;
}

__global__ void draw_kernel(const float4* __restrict__ selBox, const int* __restrict__ selValid,
                            float* __restrict__ out)
{
    int b = blockIdx.x;
    if (!selValid[b]) return;
    float4 B = selBox[b];
    int r1 = to_px(B.x), c1 = to_px(B.y), r2 = to_px(B.z), c2 = to_px(B.w);
    for (int i = threadIdx.x; i <= c2 - c1; i += blockDim.x) {
        out[r1*IMG + c1 + i] = 1.0f;
        out[r2*IMG + c1 + i] = 1.0f;
    }
    for (int i = threadIdx.x; i <= r2 - r1; i += blockDim.x) {
        out[(r1 + i)*IMG + c1] = 1.0f;
        out[(r1 + i)*IMG + c2] = 1.0f;
    }
}

extern "C" void kernel_launch(void* const* d_in, const int* in_sizes, int n_in,
                              void* d_out, int out_size, void* d_ws, size_t ws_size,
                              hipStream_t stream)
{
    const float* in      = (const float*)d_in[0];
    const float* anchors = (const float*)d_in[1];
    float* out           = (float*)d_out;

    char* ws = (char*)d_ws;
    size_t off = 0;
    int*    cnt      = (int*)(ws + off);    off += (size_t)NC*CSTRIDE*sizeof(int);
    float4* candBox  = (float4*)(ws + off); off += (size_t)NC*CAP*sizeof(float4);
    u64*    candKey  = (u64*)(ws + off);    off += (size_t)NC*CAP*sizeof(u64);
    float4* selBox   = (float4*)(ws + off); off += (size_t)NC*MAXB*sizeof(float4);
    int*    selValid = (int*)(ws + off);    off += (size_t)NC*MAXB*sizeof(int);

    hipMemsetAsync(cnt, 0, (size_t)NC*CSTRIDE*sizeof(int), stream);
    hipMemsetAsync(out, 0, (size_t)IMG*IMG*sizeof(float), stream);

    decode_kernel<<<(NBOX + DB - 1)/DB, DB, 0, stream>>>(in, anchors, cnt, candBox, candKey);
    nms_kernel<<<NC, 256, 0, stream>>>(cnt, candBox, candKey, selBox, selValid);
    draw_kernel<<<NC*MAXB, 128, 0, stream>>>(selBox, selValid, out);
}

// Round 7
// 111.764 us; speedup vs baseline: 1.9407x; 1.0627x over previous
//
#pragma clang fp contract(off)
#include <hip/hip_runtime.h>
#include <math.h>

#define G       104
#define NBA     9
#define NC      80
#define NBOX    (G*G*NBA)      // 97344
#define CH      (5+NC)         // 85
#define DET_T_  0.02f
#define NMS_T_  0.3f
#define MAXB    50
#define CAP     2048           // per-class cap; true counts ~1030 +/- 32 (CAP=1024 truncated -> round 5/6 failures)
#define SORTN   2048
#define IMG     832
#define CSTRIDE 16             // pad class counters to 64B
#define DB      128            // decode boxes per block

typedef unsigned long long u64;
typedef unsigned int       u32;

__device__ __forceinline__ float sigmoidf_(float x) { return 1.0f / (1.0f + expf(-x)); }

// ---------------- zero counters + canvas (one dispatch) ----------------
__global__ __launch_bounds__(256) void zero_kernel(int* __restrict__ cnt, float4* __restrict__ out4)
{
    int i = blockIdx.x * 256 + threadIdx.x;
    if (i < NC * CSTRIDE) cnt[i] = 0;
    if (i < (IMG * IMG) / 4) out4[i] = make_float4(0, 0, 0, 0);
}

// ---------------- decode + per-class compaction (proven in round 4) ----------------
__global__ __launch_bounds__(DB) void decode_kernel(const float* __restrict__ in,
        const float* __restrict__ anchors, int* __restrict__ cnt,
        float4* __restrict__ candBox, u64* __restrict__ candKey)
{
    __shared__ float lds[DB * CH];   // 43,520 B
    const int tid = threadIdx.x;
    const int base = blockIdx.x * (DB * CH);
    int nfl = NBOX * CH - base;
    if (nfl > DB * CH) nfl = DB * CH;

    int nv4 = nfl >> 2;
    const float4* gin4 = (const float4*)(in + base);
    for (int i = tid; i < nv4; i += DB) ((float4*)lds)[i] = gin4[i];
    for (int i = (nv4 << 2) + tid; i < nfl; i += DB) lds[i] = in[base + i];
    __syncthreads();

    int n = blockIdx.x * DB + tid;
    if (n >= NBOX) return;
    const float* p = lds + tid * CH;

    float m = -INFINITY;
#pragma unroll
    for (int i = 0; i < NC; ++i) m = fmaxf(m, p[5 + i]);

    // single exp pass: sum (exact reference order) + candidate bitmask
    float sum = 0.0f;
    u64 cm0 = 0, cm1 = 0;
#pragma unroll
    for (int i = 0; i < NC; ++i) {
        float d = p[5 + i] - m;
        sum += expf(d);
        u64 cand = (d >= -2.0e-6f) ? 1ull : 0ull;
        if (i < 64) cm0 |= cand << i;
        else        cm1 |= cand << (i - 64);
    }
    float obj = sigmoidf_(p[4]);

    // exact first-max over candidate classes only (ascending index order)
    float best = -1.0f; int bcls = 0;
    while (cm0) {
        int i = __ffsll((long long)cm0) - 1; cm0 &= cm0 - 1;
        float e = expf(p[5 + i] - m);
        float s = obj * (e / sum);
        if (s > best) { best = s; bcls = i; }
    }
    while (cm1) {
        int i = __ffsll((long long)cm1) - 1 + 64; cm1 &= cm1 - 1;
        float e = expf(p[5 + i] - m);
        float s = obj * (e / sum);
        if (s > best) { best = s; bcls = i; }
    }

    if (best > DET_T_) {
        int a  = n % NBA;
        int t  = n / NBA;
        int gx = t % G;
        int gy = t / G;
        float bx = (sigmoidf_(p[0]) + (float)gx) / (float)G;
        float by = (sigmoidf_(p[1]) + (float)gy) / (float)G;
        float bw = expf(p[2]) * anchors[2*a + 0] / (float)G;
        float bh = expf(p[3]) * anchors[2*a + 1] / (float)G;
        float4 box = make_float4(bx - bw / 2.0f, by - bh / 2.0f,
                                 bx + bw / 2.0f, by + bh / 2.0f);
        int pos = atomicAdd(&cnt[bcls * CSTRIDE], 1);
        if (pos < CAP) {
            int slot = bcls * CAP + pos;
            candBox[slot] = box;
            candKey[slot] = ((u64)__float_as_uint(best) << 32) | (u32)(~(u32)n);
        }
    }
}

// ---------------- per-class: verified sort -> batched walk NMS -> draw ----------------
__device__ __forceinline__ int to_px(float v) {
    float r = rintf(v * 831.0f);           // jnp.round = half-to-even
    r = fminf(fmaxf(r, 0.0f), 831.0f);     // clip AFTER round
    return (int)r;
}

// reference-exact IoU(winner W, candidate C): a0 = winner area first
__device__ __forceinline__ bool iou_gt(const float4 W, const float4 C) {
    float a0 = (W.z - W.x) * (W.w - W.y);
    float x1 = fmaxf(W.x, C.x), y1 = fmaxf(W.y, C.y);
    float x2 = fminf(W.z, C.z), y2 = fminf(W.w, C.w);
    float inter = fmaxf(x2 - x1, 0.0f) * fmaxf(y2 - y1, 0.0f);
    float a1 = (C.z - C.x) * (C.w - C.y);
    float uni = a0 + a1 - inter;
    float iou = (uni > 0.0f) ? (inter / uni) : 0.0f;
    return iou > NMS_T_;
}

__global__ __launch_bounds__(256) void nms_draw_kernel(const int* __restrict__ cnt,
    const float4* __restrict__ candBox, const u64* __restrict__ candKey,
    float* __restrict__ out)
{
    __shared__ u64    skey[SORTN];    // 16 KB
    __shared__ u32    sslot[SORTN];   // 8 KB
    __shared__ float4 sbox[SORTN];    // 32 KB
    __shared__ float4 selb[MAXB];
    __shared__ int    s_nsel, s_bad;

    const int c = blockIdx.x;
    const int t = threadIdx.x;
    int count = cnt[c * CSTRIDE]; if (count > CAP) count = CAP;

    for (int i = t; i < SORTN; i += 256) {
        skey[i]  = (i < count) ? candKey[c*CAP + i] : 0ull;   // pads (0) sink to end
        sslot[i] = (u32)i;
    }
    if (t == 0) s_bad = 0;
    __syncthreads();

    // bitonic sort, descending by unique key (score_bits | ~id)
    for (int size = 2; size <= SORTN; size <<= 1) {
        for (int stride = size >> 1; stride >= 1; stride >>= 1) {
#pragma unroll 1
            for (int v = t; v < SORTN/2; v += 256) {
                int i = ((v & ~(stride - 1)) << 1) | (v & (stride - 1));
                int j = i | stride;
                bool asc = (i & size) != 0;
                u64 ki = skey[i], kj = skey[j];
                bool sw = asc ? (ki > kj) : (ki < kj);
                if (sw) {
                    skey[i] = kj; skey[j] = ki;
                    u32 s0 = sslot[i]; sslot[i] = sslot[j]; sslot[j] = s0;
                }
            }
            __syncthreads();
        }
    }

    // self-verify: descending order AND key<->slot pairing intact
    for (int i = t; i < SORTN - 1; i += 256) if (skey[i] < skey[i + 1]) s_bad = 1;
    for (int i = t; i < count; i += 256)
        if (candKey[c*CAP + sslot[i]] != skey[i]) s_bad = 1;
    __syncthreads();

    if (s_bad) {   // dormant fallback: odd-even transposition (provably correct)
        for (int i = t; i < SORTN; i += 256) {
            skey[i]  = (i < count) ? candKey[c*CAP + i] : 0ull;
            sslot[i] = (u32)i;
        }
        __syncthreads();
        for (int ph = 0; ph < SORTN; ++ph) {
#pragma unroll 1
            for (int v = t; v < SORTN/2; v += 256) {
                int i = (v << 1) + (ph & 1);
                if (i + 1 < SORTN) {
                    u64 a = skey[i], b = skey[i + 1];
                    if (a < b) {
                        skey[i] = b; skey[i + 1] = a;
                        u32 s0 = sslot[i]; sslot[i] = sslot[i + 1]; sslot[i + 1] = s0;
                    }
                }
            }
            __syncthreads();
        }
    }

    // gather boxes into sorted order
    for (int i = t; i < count; i += 256) sbox[i] = candBox[c*CAP + sslot[i]];
    if (t == 0) s_nsel = 0;
    __syncthreads();

    // wave-0 batched walk (exact sorted-greedy == reference iterative argmax NMS):
    // stage 1: 64 candidates checked vs existing winners in parallel;
    // stage 2: intra-batch greedy via broadcast + ballot kills.
    if (t < 64) {
        const int lane = t;
        int nsel = 0;
        for (int p0 = 0; p0 < count && nsel < MAXB; p0 += 64) {
            int p = p0 + lane;
            bool have = (p < count);
            float4 C = sbox[have ? p : 0];

            bool sup = false;
            for (int w = 0; w < nsel && !sup; ++w)
                sup = iou_gt(selb[w], C);              // winner = "box", cand = other

            u64 alive = __ballot(have && !sup);
            while (alive != 0ull && nsel < MAXB) {
                int i = __ffsll((long long)alive) - 1;  // lowest sorted index first
                float4 Wn = make_float4(__shfl(C.x, i), __shfl(C.y, i),
                                        __shfl(C.z, i), __shfl(C.w, i));
                if (lane == 0) selb[nsel] = Wn;         // same-wave LDS RAW is ordered
                ++nsel;
                u64 killed = __ballot(have && iou_gt(Wn, C));  // self-IoU=1 kills lane i
                alive &= ~killed;
            }
        }
        if (lane == 0) s_nsel = nsel;
    }
    __syncthreads();

    // cooperative draw: wave per box (1.0f store races benign)
    int nsel = s_nsel;
    int lane = t & 63;
    for (int b = t >> 6; b < nsel; b += 4) {
        float4 B = selb[b];
        int r1 = to_px(B.x), c1 = to_px(B.y), r2 = to_px(B.z), c2 = to_px(B.w);
        for (int i = c1 + lane; i <= c2; i += 64) {
            out[r1*IMG + i] = 1.0f;
            out[r2*IMG + i] = 1.0f;
        }
        for (int i = r1 + lane; i <= r2; i += 64) {
            out[i*IMG + c1] = 1.0f;
            out[i*IMG + c2] = 1.0f;
        }
    }
}

extern "C" void kernel_launch(void* const* d_in, const int* in_sizes, int n_in,
                              void* d_out, int out_size, void* d_ws, size_t ws_size,
                              hipStream_t stream)
{
    const float* in      = (const float*)d_in[0];
    const float* anchors = (const float*)d_in[1];
    float* out           = (float*)d_out;

    char* ws = (char*)d_ws;
    size_t off = 0;
    int*    cnt     = (int*)(ws + off);    off += (size_t)NC*CSTRIDE*sizeof(int);
    float4* candBox = (float4*)(ws + off); off += (size_t)NC*CAP*sizeof(float4);
    u64*    candKey = (u64*)(ws + off);    off += (size_t)NC*CAP*sizeof(u64);

    int zblocks = ((IMG*IMG)/4 + 255) / 256;   // covers canvas (float4) and counters
    zero_kernel<<<zblocks, 256, 0, stream>>>(cnt, (float4*)out);
    decode_kernel<<<(NBOX + DB - 1)/DB, DB, 0, stream>>>(in, anchors, cnt, candBox, candKey);
    nms_draw_kernel<<<NC, 256, 0, stream>>>(cnt, candBox, candKey, out);
}

// Round 8
// 87.219 us; speedup vs baseline: 2.4868x; 1.2814x over previous
//
#pragma clang fp contract(off)
#include <hip/hip_runtime.h>
#include <math.h>

#define G       104
#define NBA     9
#define NC      80
#define NBOX    (G*G*NBA)      // 97344
#define CH      (5+NC)         // 85
#define DET_T_  0.02f
#define NMS_T_  0.3f
#define MAXB    50
#define CAP     2048           // per-class cap; true counts ~1030 +/- 32
#define SORTN   2048
#define IMG     832
#define CSTRIDE 16             // pad class counters to 64B
#define DB      128            // decode boxes per block

// LDS bank swizzle for the u64 key array (involution, bijective on [0,2048))
#define SWZ(i)  ((i) ^ (((i) >> 4) & 15))

typedef unsigned long long u64;
typedef unsigned int       u32;

__device__ __forceinline__ float sigmoidf_(float x) { return 1.0f / (1.0f + expf(-x)); }

// ---------------- zero counters + canvas (one dispatch) ----------------
__global__ __launch_bounds__(256) void zero_kernel(int* __restrict__ cnt, float4* __restrict__ out4)
{
    int i = blockIdx.x * 256 + threadIdx.x;
    if (i < NC * CSTRIDE) cnt[i] = 0;
    if (i < (IMG * IMG) / 4) out4[i] = make_float4(0, 0, 0, 0);
}

// ---------------- decode + per-class compaction ----------------
// Box stored by global id (no atomic); only the u64 key goes through the
// per-class atomic list. key = score_bits<<32 | ~id  (max == max score, tie->min id)
__global__ __launch_bounds__(DB) void decode_kernel(const float* __restrict__ in,
        const float* __restrict__ anchors, int* __restrict__ cnt,
        float4* __restrict__ boxById, u64* __restrict__ candKey)
{
    __shared__ float lds[DB * CH];   // 43,520 B
    const int tid = threadIdx.x;
    const int base = blockIdx.x * (DB * CH);
    int nfl = NBOX * CH - base;
    if (nfl > DB * CH) nfl = DB * CH;

    int nv4 = nfl >> 2;
    const float4* gin4 = (const float4*)(in + base);
    for (int i = tid; i < nv4; i += DB) ((float4*)lds)[i] = gin4[i];
    for (int i = (nv4 << 2) + tid; i < nfl; i += DB) lds[i] = in[base + i];
    __syncthreads();

    int n = blockIdx.x * DB + tid;
    if (n >= NBOX) return;
    const float* p = lds + tid * CH;

    float m = -INFINITY;
#pragma unroll
    for (int i = 0; i < NC; ++i) m = fmaxf(m, p[5 + i]);

    // single exp pass: sum (exact reference order) + candidate bitmask
    float sum = 0.0f;
    u64 cm0 = 0, cm1 = 0;
#pragma unroll
    for (int i = 0; i < NC; ++i) {
        float d = p[5 + i] - m;
        sum += expf(d);
        u64 cand = (d >= -2.0e-6f) ? 1ull : 0ull;
        if (i < 64) cm0 |= cand << i;
        else        cm1 |= cand << (i - 64);
    }
    float obj = sigmoidf_(p[4]);

    // exact first-max over candidate classes only (ascending index order)
    float best = -1.0f; int bcls = 0;
    while (cm0) {
        int i = __ffsll((long long)cm0) - 1; cm0 &= cm0 - 1;
        float e = expf(p[5 + i] - m);
        float s = obj * (e / sum);
        if (s > best) { best = s; bcls = i; }
    }
    while (cm1) {
        int i = __ffsll((long long)cm1) - 1 + 64; cm1 &= cm1 - 1;
        float e = expf(p[5 + i] - m);
        float s = obj * (e / sum);
        if (s > best) { best = s; bcls = i; }
    }

    if (best > DET_T_) {
        int a  = n % NBA;
        int t  = n / NBA;
        int gx = t % G;
        int gy = t / G;
        float bx = (sigmoidf_(p[0]) + (float)gx) / (float)G;
        float by = (sigmoidf_(p[1]) + (float)gy) / (float)G;
        float bw = expf(p[2]) * anchors[2*a + 0] / (float)G;
        float bh = expf(p[3]) * anchors[2*a + 1] / (float)G;
        boxById[n] = make_float4(bx - bw / 2.0f, by - bh / 2.0f,
                                 bx + bw / 2.0f, by + bh / 2.0f);
        int pos = atomicAdd(&cnt[bcls * CSTRIDE], 1);
        if (pos < CAP)
            candKey[bcls * CAP + pos] = ((u64)__float_as_uint(best) << 32) | (u32)(~(u32)n);
    }
}

// ---------------- per-class: key-only sort -> batched walk NMS -> draw ----------------
__device__ __forceinline__ int to_px(float v) {
    float r = rintf(v * 831.0f);           // jnp.round = half-to-even
    r = fminf(fmaxf(r, 0.0f), 831.0f);     // clip AFTER round
    return (int)r;
}

// reference-exact IoU(winner W, candidate C) > T
__device__ __forceinline__ bool iou_gt(const float4 W, const float4 C) {
    float a0 = (W.z - W.x) * (W.w - W.y);
    float x1 = fmaxf(W.x, C.x), y1 = fmaxf(W.y, C.y);
    float x2 = fminf(W.z, C.z), y2 = fminf(W.w, C.w);
    float inter = fmaxf(x2 - x1, 0.0f) * fmaxf(y2 - y1, 0.0f);
    float a1 = (C.z - C.x) * (C.w - C.y);
    float uni = a0 + a1 - inter;
    float iou = (uni > 0.0f) ? (inter / uni) : 0.0f;
    return iou > NMS_T_;
}

__global__ __launch_bounds__(1024) void nms_draw_kernel(const int* __restrict__ cnt,
    const float4* __restrict__ boxById, const u64* __restrict__ candKey,
    float* __restrict__ out)
{
    __shared__ u64    skey[SORTN];    // 16 KB (bank-swizzled indexing)
    __shared__ float4 sbox[SORTN];    // 32 KB
    __shared__ float4 selb[MAXB];
    __shared__ int    s_nsel, s_bad;

    const int c = blockIdx.x;
    const int t = threadIdx.x;
    int count = cnt[c * CSTRIDE]; if (count > CAP) count = CAP;

    for (int i = t; i < SORTN; i += 1024)
        skey[SWZ(i)] = (i < count) ? candKey[c*CAP + i] : 0ull;   // pads sink to end
    if (t == 0) s_bad = 0;
    __syncthreads();

    // bitonic sort, descending by unique key; one compare-swap per thread per pass
    for (int size = 2; size <= SORTN; size <<= 1) {
        for (int stride = size >> 1; stride >= 1; stride >>= 1) {
            int i = ((t & ~(stride - 1)) << 1) | (t & (stride - 1));
            int j = i | stride;
            bool asc = (i & size) != 0;
            u64 ki = skey[SWZ(i)], kj = skey[SWZ(j)];
            bool sw = asc ? (ki > kj) : (ki < kj);
            if (sw) { skey[SWZ(i)] = kj; skey[SWZ(j)] = ki; }
            __syncthreads();
        }
    }

    // self-verify descending order (key-only; no payload pairing to check)
    for (int i = t; i < SORTN - 1; i += 1024)
        if (skey[SWZ(i)] < skey[SWZ(i + 1)]) s_bad = 1;
    __syncthreads();

    if (s_bad) {   // dormant fallback: odd-even transposition (provably correct)
        for (int i = t; i < SORTN; i += 1024)
            skey[SWZ(i)] = (i < count) ? candKey[c*CAP + i] : 0ull;
        __syncthreads();
        for (int ph = 0; ph < SORTN; ++ph) {
            int i = (t << 1) + (ph & 1);
            if (i + 1 < SORTN) {
                u64 a = skey[SWZ(i)], b = skey[SWZ(i + 1)];
                if (a < b) { skey[SWZ(i)] = b; skey[SWZ(i + 1)] = a; }
            }
            __syncthreads();
        }
    }

    // gather boxes into sorted order via id (low 32 bits of key = ~n)
    for (int i = t; i < count; i += 1024) {
        u32 nid = ~(u32)(skey[SWZ(i)]);
        sbox[i] = boxById[nid];
    }
    if (t == 0) s_nsel = 0;
    __syncthreads();

    // wave-0 batched walk (exact sorted-greedy == reference iterative argmax NMS)
    if (t < 64) {
        const int lane = t;
        int nsel = 0;
        for (int p0 = 0; p0 < count && nsel < MAXB; p0 += 64) {
            int p = p0 + lane;
            bool have = (p < count);
            float4 C = sbox[have ? p : 0];

            bool sup = false;
            for (int w = 0; w < nsel && !sup; ++w)
                sup = iou_gt(selb[w], C);

            u64 alive = __ballot(have && !sup);
            while (alive != 0ull && nsel < MAXB) {
                int i = __ffsll((long long)alive) - 1;   // lowest sorted index first
                float4 Wn = make_float4(__shfl(C.x, i), __shfl(C.y, i),
                                        __shfl(C.z, i), __shfl(C.w, i));
                if (lane == 0) selb[nsel] = Wn;          // same-wave LDS RAW ordered
                ++nsel;
                u64 killed = __ballot(have && iou_gt(Wn, C));  // self-IoU=1 kills lane i
                alive &= ~killed;
            }
        }
        if (lane == 0) s_nsel = nsel;
    }
    __syncthreads();

    // cooperative draw across all 16 waves (1.0f store races benign)
    int nsel = s_nsel;
    int lane = t & 63;
    for (int b = t >> 6; b < nsel; b += 16) {
        float4 B = selb[b];
        int r1 = to_px(B.x), c1 = to_px(B.y), r2 = to_px(B.z), c2 = to_px(B.w);
        for (int i = c1 + lane; i <= c2; i += 64) {
            out[r1*IMG + i] = 1.0f;
            out[r2*IMG + i] = 1.0f;
        }
        for (int i = r1 + lane; i <= r2; i += 64) {
            out[i*IMG + c1] = 1.0f;
            out[i*IMG + c2] = 1.0f;
        }
    }
}

extern "C" void kernel_launch(void* const* d_in, const int* in_sizes, int n_in,
                              void* d_out, int out_size, void* d_ws, size_t ws_size,
                              hipStream_t stream)
{
    const float* in      = (const float*)d_in[0];
    const float* anchors = (const float*)d_in[1];
    float* out           = (float*)d_out;

    char* ws = (char*)d_ws;
    size_t off = 0;
    int*    cnt     = (int*)(ws + off);    off += (size_t)NC*CSTRIDE*sizeof(int);
    float4* boxById = (float4*)(ws + off); off += (size_t)NBOX*sizeof(float4);
    u64*    candKey = (u64*)(ws + off);    off += (size_t)NC*CAP*sizeof(u64);

    int zblocks = ((IMG*IMG)/4 + 255) / 256;   // covers canvas (float4) and counters
    zero_kernel<<<zblocks, 256, 0, stream>>>(cnt, (float4*)out);
    decode_kernel<<<(NBOX + DB - 1)/DB, DB, 0, stream>>>(in, anchors, cnt, boxById, candKey);
    nms_draw_kernel<<<NC, 1024, 0, stream>>>(cnt, boxById, candKey, out);
}

// Round 9
// 83.805 us; speedup vs baseline: 2.5881x; 1.0407x over previous
//
#pragma clang fp contract(off)
#include <hip/hip_runtime.h>
#include <math.h>

#define G       104
#define NBA     9
#define NC      80
#define NBOX    (G*G*NBA)      // 97344
#define CH      (5+NC)         // 85
#define DET_T_  0.02f
#define NMS_T_  0.3f
#define MAXB    50
#define CAP     2048           // per-class cap; true counts ~1030 +/- 32
#define SORTN   2048
#define IMG     832
#define CSTRIDE 16             // pad class counters to 64B
#define DB      128            // decode boxes per block

typedef unsigned long long u64;
typedef unsigned int       u32;

__device__ __forceinline__ float sigmoidf_(float x) { return 1.0f / (1.0f + expf(-x)); }

// ---------------- zero class counters (tiny) ----------------
__global__ __launch_bounds__(128) void zero_cnt_kernel(int* __restrict__ cnt)
{
    for (int i = threadIdx.x; i < NC * CSTRIDE; i += 128) cnt[i] = 0;
}

// ---------------- decode + per-class compaction + canvas zero ----------------
// key = score_bits<<32 | ~id  (u64 max == max score, tie -> min original id)
__global__ __launch_bounds__(DB) void decode_kernel(const float* __restrict__ in,
        const float* __restrict__ anchors, int* __restrict__ cnt,
        float4* __restrict__ boxById, u64* __restrict__ candKey, float4* __restrict__ out4)
{
    __shared__ float lds[DB * CH];   // 43,520 B
    const int tid = threadIdx.x;

    // canvas zero slice (stream-ordered before nms_draw; no intra-kernel deps)
    {
        const int CZ = (IMG*IMG/4 + 760) / 761;   // 228 float4 per block
        int zbase = blockIdx.x * CZ;
        for (int i = tid; i < CZ; i += DB) {
            int idx = zbase + i;
            if (idx < IMG*IMG/4) out4[idx] = make_float4(0, 0, 0, 0);
        }
    }

    const int base = blockIdx.x * (DB * CH);
    int nfl = NBOX * CH - base;
    if (nfl > DB * CH) nfl = DB * CH;

    int nv4 = nfl >> 2;
    const float4* gin4 = (const float4*)(in + base);
    for (int i = tid; i < nv4; i += DB) ((float4*)lds)[i] = gin4[i];
    for (int i = (nv4 << 2) + tid; i < nfl; i += DB) lds[i] = in[base + i];
    __syncthreads();

    int n = blockIdx.x * DB + tid;
    if (n >= NBOX) return;
    const float* p = lds + tid * CH;

    float m = -INFINITY;
#pragma unroll
    for (int i = 0; i < NC; ++i) m = fmaxf(m, p[5 + i]);

    // single exp pass: sum (exact reference order) + candidate bitmask
    float sum = 0.0f;
    u64 cm0 = 0, cm1 = 0;
#pragma unroll
    for (int i = 0; i < NC; ++i) {
        float d = p[5 + i] - m;
        sum += expf(d);
        u64 cand = (d >= -2.0e-6f) ? 1ull : 0ull;
        if (i < 64) cm0 |= cand << i;
        else        cm1 |= cand << (i - 64);
    }
    float obj = sigmoidf_(p[4]);

    // exact first-max over candidate classes only (ascending index order)
    float best = -1.0f; int bcls = 0;
    while (cm0) {
        int i = __ffsll((long long)cm0) - 1; cm0 &= cm0 - 1;
        float e = expf(p[5 + i] - m);
        float s = obj * (e / sum);
        if (s > best) { best = s; bcls = i; }
    }
    while (cm1) {
        int i = __ffsll((long long)cm1) - 1 + 64; cm1 &= cm1 - 1;
        float e = expf(p[5 + i] - m);
        float s = obj * (e / sum);
        if (s > best) { best = s; bcls = i; }
    }

    if (best > DET_T_) {
        int a  = n % NBA;
        int t  = n / NBA;
        int gx = t % G;
        int gy = t / G;
        float bx = (sigmoidf_(p[0]) + (float)gx) / (float)G;
        float by = (sigmoidf_(p[1]) + (float)gy) / (float)G;
        float bw = expf(p[2]) * anchors[2*a + 0] / (float)G;
        float bh = expf(p[3]) * anchors[2*a + 1] / (float)G;
        boxById[n] = make_float4(bx - bw / 2.0f, by - bh / 2.0f,
                                 bx + bw / 2.0f, by + bh / 2.0f);
        int pos = atomicAdd(&cnt[bcls * CSTRIDE], 1);
        if (pos < CAP)
            candKey[bcls * CAP + pos] = ((u64)__float_as_uint(best) << 32) | (u32)(~(u32)n);
    }
}

// ---------------- per-class: hybrid reg/LDS sort -> batched walk NMS -> draw ----------------
__device__ __forceinline__ int to_px(float v) {
    float r = rintf(v * 831.0f);           // jnp.round = half-to-even
    r = fminf(fmaxf(r, 0.0f), 831.0f);     // clip AFTER round
    return (int)r;
}

// reference-exact IoU(winner W, candidate C) > T
__device__ __forceinline__ bool iou_gt(const float4 W, const float4 C) {
    float a0 = (W.z - W.x) * (W.w - W.y);
    float x1 = fmaxf(W.x, C.x), y1 = fmaxf(W.y, C.y);
    float x2 = fminf(W.z, C.z), y2 = fminf(W.w, C.w);
    float inter = fmaxf(x2 - x1, 0.0f) * fmaxf(y2 - y1, 0.0f);
    float a1 = (C.z - C.x) * (C.w - C.y);
    float uni = a0 + a1 - inter;
    float iou = (uni > 0.0f) ? (inter / uni) : 0.0f;
    return iou > NMS_T_;
}

// bitonic compare-exchange via shfl_xor (stride <= 32), element index x
__device__ __forceinline__ u64 cex_shfl(u64 r, int x, int stride, int size) {
    u64 v = __shfl_xor(r, stride);
    bool asc   = (x & size) != 0;
    bool upper = (x & stride) != 0;
    bool keep_max = (!asc) != upper;     // XOR
    u64 mx = (r > v) ? r : v;
    u64 mn = (r > v) ? v : r;
    return keep_max ? mx : mn;
}

__global__ __launch_bounds__(1024) void nms_draw_kernel(const int* __restrict__ cnt,
    const float4* __restrict__ boxById, const u64* __restrict__ candKey,
    float* __restrict__ out)
{
    __shared__ u64    skey[SORTN];    // 16 KB (cross-wave merge passes only)
    __shared__ float4 sbox[SORTN];    // 32 KB
    __shared__ float4 selb[MAXB];
    __shared__ u64    csA[16], csB[16], sfirst[16];
    __shared__ int    s_nsel, s_bad;

    const int c = blockIdx.x;
    const int t = threadIdx.x;
    const int w = t >> 6, l = t & 63;
    const int eA = (w << 7) + l, eB = eA + 64;   // wave w owns elements [128w,128w+128)
    int count = cnt[c * CSTRIDE]; if (count > CAP) count = CAP;

    u64 rA = (eA < count) ? candKey[c*CAP + eA] : 0ull;
    u64 rB = (eB < count) ? candKey[c*CAP + eB] : 0ull;
    if (t == 0) { s_bad = 0; s_nsel = 0; }

    // checksum of input multiset (XOR is order-independent)
    {
        u64 x = rA ^ rB;
#pragma unroll
        for (int off = 32; off >= 1; off >>= 1) x ^= __shfl_xor(x, off);
        if (l == 0) csA[w] = x;
    }

    // ---- Phase A: in-register bitonic sort of each 128-chunk (no barriers) ----
#pragma unroll
    for (int size = 2; size <= 64; size <<= 1)
        for (int stride = size >> 1; stride >= 1; stride >>= 1) {
            rA = cex_shfl(rA, eA, stride, size);
            rB = cex_shfl(rB, eB, stride, size);
        }
    {   // size = 128: stride 64 is the in-lane register pair
        const int size = 128;
        bool asc = (eA & 128) != 0;
        u64 mx = (rA > rB) ? rA : rB, mn = (rA > rB) ? rB : rA;
        rA = asc ? mn : mx; rB = asc ? mx : mn;
        for (int stride = 32; stride >= 1; stride >>= 1) {
            rA = cex_shfl(rA, eA, stride, size);
            rB = cex_shfl(rB, eB, stride, size);
        }
    }

    // ---- Phase B: merge sizes 256..2048; only stride>=128 passes touch LDS ----
    for (int size = 256; size <= 2048; size <<= 1) {
        skey[eA] = rA; skey[eB] = rB;
        __syncthreads();
        for (int stride = size >> 1; stride >= 128; stride >>= 1) {
            int i = ((t & ~(stride - 1)) << 1) | (t & (stride - 1));
            int j = i | stride;
            bool asc = (i & size) != 0;
            u64 ki = skey[i], kj = skey[j];
            bool sw = asc ? (ki > kj) : (ki < kj);
            if (sw) { skey[i] = kj; skey[j] = ki; }
            __syncthreads();
        }
        rA = skey[eA]; rB = skey[eB];
        bool asc = (eA & size) != 0;   // stride 64: in-lane pair (same asc for eA,eB)
        u64 mx = (rA > rB) ? rA : rB, mn = (rA > rB) ? rB : rA;
        rA = asc ? mn : mx; rB = asc ? mx : mn;
        for (int stride = 32; stride >= 1; stride >>= 1) {
            rA = cex_shfl(rA, eA, stride, size);
            rB = cex_shfl(rB, eB, stride, size);
        }
    }

    // ---- verify: descending order + XOR checksum ----
    {
        u64 x = rA ^ rB;
#pragma unroll
        for (int off = 32; off >= 1; off >>= 1) x ^= __shfl_xor(x, off);
        if (l == 0) { csB[w] = x; sfirst[w] = rA; }  // sfirst[w] = element 128w (lane0 rA)
        bool bad = false;
        u64 dA  = __shfl_down(rA, 1);
        u64 dB  = __shfl_down(rB, 1);
        u64 rB0 = __shfl(rB, 0);
        if (l < 63) { bad |= (rA < dA); bad |= (rB < dB); }
        if (l == 63) bad |= (rA < rB0);          // e=128w+63 vs 128w+64
        __syncthreads();
        if (l == 63 && w < 15) bad |= (rB < sfirst[w + 1]);   // chunk boundary
        if (t == 0) {
            u64 X0 = 0, X1 = 0;
            for (int i = 0; i < 16; ++i) { X0 ^= csA[i]; X1 ^= csB[i]; }
            if (X0 != X1) s_bad = 1;
        }
        if (bad) s_bad = 1;
        __syncthreads();
    }

    if (s_bad) {   // dormant fallback: odd-even transposition in LDS (provably correct)
        for (int i = t; i < SORTN; i += 1024)
            skey[i] = (i < count) ? candKey[c*CAP + i] : 0ull;
        __syncthreads();
        for (int ph = 0; ph < SORTN; ++ph) {
            int i = (t << 1) + (ph & 1);
            if (i + 1 < SORTN) {
                u64 a = skey[i], b = skey[i + 1];
                if (a < b) { skey[i] = b; skey[i + 1] = a; }
            }
            __syncthreads();
        }
        rA = skey[eA]; rB = skey[eB];
    }

    // ---- gather boxes into sorted order (id = ~low32(key)) ----
    if (eA < count) sbox[eA] = boxById[~(u32)rA];
    if (eB < count) sbox[eB] = boxById[~(u32)rB];
    __syncthreads();

    // ---- wave-0 batched walk (exact sorted-greedy == reference argmax NMS) ----
    if (t < 64) {
        const int lane = t;
        int nsel = 0;
        for (int p0 = 0; p0 < count && nsel < MAXB; p0 += 64) {
            int p = p0 + lane;
            bool have = (p < count);
            float4 C = sbox[have ? p : 0];

            bool sup = false;
            for (int ww = 0; ww < nsel && !sup; ++ww)
                sup = iou_gt(selb[ww], C);

            u64 alive = __ballot(have && !sup);
            while (alive != 0ull && nsel < MAXB) {
                int i = __ffsll((long long)alive) - 1;   // lowest sorted index first
                float4 Wn = make_float4(__shfl(C.x, i), __shfl(C.y, i),
                                        __shfl(C.z, i), __shfl(C.w, i));
                if (lane == 0) selb[nsel] = Wn;          // same-wave LDS RAW ordered
                ++nsel;
                u64 killed = __ballot(have && iou_gt(Wn, C));  // self-IoU=1 kills lane i
                alive &= ~killed;
            }
        }
        if (lane == 0) s_nsel = nsel;
    }
    __syncthreads();

    // ---- cooperative draw across all 16 waves (1.0f store races benign) ----
    int nsel = s_nsel;
    int lane = t & 63;
    for (int b = t >> 6; b < nsel; b += 16) {
        float4 B = selb[b];
        int r1 = to_px(B.x), c1 = to_px(B.y), r2 = to_px(B.z), c2 = to_px(B.w);
        for (int i = c1 + lane; i <= c2; i += 64) {
            out[r1*IMG + i] = 1.0f;
            out[r2*IMG + i] = 1.0f;
        }
        for (int i = r1 + lane; i <= r2; i += 64) {
            out[i*IMG + c1] = 1.0f;
            out[i*IMG + c2] = 1.0f;
        }
    }
}

extern "C" void kernel_launch(void* const* d_in, const int* in_sizes, int n_in,
                              void* d_out, int out_size, void* d_ws, size_t ws_size,
                              hipStream_t stream)
{
    const float* in      = (const float*)d_in[0];
    const float* anchors = (const float*)d_in[1];
    float* out           = (float*)d_out;

    char* ws = (char*)d_ws;
    size_t off = 0;
    int*    cnt     = (int*)(ws + off);    off += (size_t)NC*CSTRIDE*sizeof(int);
    float4* boxById = (float4*)(ws + off); off += (size_t)NBOX*sizeof(float4);
    u64*    candKey = (u64*)(ws + off);    off += (size_t)NC*CAP*sizeof(u64);

    zero_cnt_kernel<<<1, 128, 0, stream>>>(cnt);
    decode_kernel<<<(NBOX + DB - 1)/DB, DB, 0, stream>>>(in, anchors, cnt, boxById, candKey,
                                                         (float4*)out);
    nms_draw_kernel<<<NC, 1024, 0, stream>>>(cnt, boxById, candKey, out);
}